// Round 3
// baseline (20198.741 us; speedup 1.0000x reference)
//
#include <hip/hip_runtime.h>
#include <math.h>

// GRU B=64,T=512,I=512,H=1024 fp32. One kernel launch per timestep.
// h-history lives in d_out: out[b][t][:] == h_t; step t reads out[..,t-1,..].
// Grid 256 = (jt 0..63: 16 j's) x (mq 0..3: 16 batch rows).
// Block 256 thr = 16 r x 4 jq x 4 kq: per-thread tile = 4 j x 3 gates x K/4,
// K=1536 (512 x-part, 1024 h-part) split over kq, LDS-reduced (deterministic).
// xs stride 1540 (not 1536): rows spread over bank quads, 2-way only (free).
// No workspace, fp32 end-to-end (same numeric class as the passing R1).

#define TT 512
#define II 512
#define HH 1024
#define XSTRIDE 1540   // 16 rows * 1540 * 4B = 98.5 KB LDS

__device__ __forceinline__ void fma4(float4& a, const float4 v, const float4 w) {
    a.x += v.x * w.x; a.y += v.y * w.y; a.z += v.z * w.z; a.w += v.w * w.w;
}
__device__ __forceinline__ float hadd4(const float4 a) {
    return (a.x + a.y) + (a.z + a.w);
}

__global__ __launch_bounds__(256, 1) void gru_step(
    const float* __restrict__ x,
    const float* __restrict__ Wir, const float* __restrict__ Whr,
    const float* __restrict__ Wiz, const float* __restrict__ Whz,
    const float* __restrict__ Win, const float* __restrict__ Whn,
    const float* __restrict__ bir, const float* __restrict__ bhr,
    const float* __restrict__ biz, const float* __restrict__ bhz,
    const float* __restrict__ bin_, const float* __restrict__ bhn,
    float* __restrict__ out, int t)
{
    __shared__ float xs[16 * XSTRIDE];
    __shared__ float red[3 * 64 * 16];   // partials from kq=1..3

    const int tid = threadIdx.x;
    const int jt  = blockIdx.x & 63;
    const int mq  = blockIdx.x >> 6;
    const int R0  = mq * 16;

    // ---- stage x_t rows (16 x 512) and h_{t-1} rows (16 x 1024) into LDS ----
#pragma unroll
    for (int i = 0; i < 8; ++i) {
        int f = tid + 256 * i;               // 0..2047 float4s
        int r = f >> 7, c = f & 127;
        float4 v = *(const float4*)(x + ((size_t)(R0 + r) * TT + t) * II + c * 4);
        *(float4*)&xs[r * XSTRIDE + c * 4] = v;
    }
    if (t > 0) {
#pragma unroll
        for (int i = 0; i < 16; ++i) {
            int f = tid + 256 * i;           // 0..4095 float4s
            int r = f >> 8, c = f & 255;
            float4 v = *(const float4*)(out + ((size_t)(R0 + r) * TT + (t - 1)) * HH + c * 4);
            *(float4*)&xs[r * XSTRIDE + 512 + c * 4] = v;
        }
    } else {
        float4 z4 = {0.f, 0.f, 0.f, 0.f};
#pragma unroll
        for (int i = 0; i < 16; ++i) {
            int f = tid + 256 * i;
            int r = f >> 8, c = f & 255;
            *(float4*)&xs[r * XSTRIDE + 512 + c * 4] = z4;
        }
    }
    __syncthreads();

    const int r  = tid & 15;
    const int jq = (tid >> 4) & 3;
    const int kq = tid >> 6;                 // wave id = K-quarter
    const int j0 = jt * 16 + jq * 4;

    float4 aR[4], aZ[4], aNx[4], aNh[4];
#pragma unroll
    for (int jj = 0; jj < 4; ++jj) {
        aR[jj] = aZ[jj] = aNx[jj] = aNh[jj] = (float4){0.f, 0.f, 0.f, 0.f};
    }

    const float* xsrow = &xs[r * XSTRIDE + kq * 384];
    const int kbase = kq * 384;
    const int nx = (kq == 0) ? 96 : (kq == 1) ? 32 : 0;   // x-part float4 iters

    // ---- x-part: W_i_* ----
#pragma unroll 2
    for (int k4 = 0; k4 < nx; ++k4) {
        float4 xv = *(const float4*)(xsrow + k4 * 4);
        int k = kbase + k4 * 4;
#pragma unroll
        for (int jj = 0; jj < 4; ++jj) {
            size_t wo = (size_t)(j0 + jj) * II + k;
            fma4(aR[jj],  xv, *(const float4*)(Wir + wo));
            fma4(aZ[jj],  xv, *(const float4*)(Wiz + wo));
            fma4(aNx[jj], xv, *(const float4*)(Win + wo));
        }
    }
    // ---- h-part: W_h_* ----
#pragma unroll 2
    for (int k4 = nx; k4 < 96; ++k4) {
        float4 xv = *(const float4*)(xsrow + k4 * 4);
        int kh = kbase + k4 * 4 - 512;
#pragma unroll
        for (int jj = 0; jj < 4; ++jj) {
            size_t wo = (size_t)(j0 + jj) * HH + kh;
            fma4(aR[jj],  xv, *(const float4*)(Whr + wo));
            fma4(aZ[jj],  xv, *(const float4*)(Whz + wo));
            fma4(aNh[jj], xv, *(const float4*)(Whn + wo));
        }
    }

    // ---- horizontal add, K-quarter reduce via LDS ----
    float p[16];
#pragma unroll
    for (int jj = 0; jj < 4; ++jj) {
        p[jj * 4 + 0] = hadd4(aR[jj]);
        p[jj * 4 + 1] = hadd4(aZ[jj]);
        p[jj * 4 + 2] = hadd4(aNx[jj]);
        p[jj * 4 + 3] = hadd4(aNh[jj]);
    }
    if (kq > 0) {
        float* dst = &red[((kq - 1) * 64 + (tid & 63)) * 16];
#pragma unroll
        for (int i = 0; i < 16; ++i) dst[i] = p[i];
    }
    __syncthreads();

    // ---- epilogue: kq==0 threads own 4 cells (r, j0..j0+3) ----
    if (kq == 0) {
#pragma unroll
        for (int w = 0; w < 3; ++w) {
            const float* src = &red[(w * 64 + (tid & 63)) * 16];
#pragma unroll
            for (int i = 0; i < 16; ++i) p[i] += src[i];
        }
        float4 vbir = *(const float4*)(bir + j0);
        float4 vbhr = *(const float4*)(bhr + j0);
        float4 vbiz = *(const float4*)(biz + j0);
        float4 vbhz = *(const float4*)(bhz + j0);
        float4 vbin = *(const float4*)(bin_ + j0);
        float4 vbhn = *(const float4*)(bhn + j0);
        const float* pbir = (const float*)&vbir;
        const float* pbhr = (const float*)&vbhr;
        const float* pbiz = (const float*)&vbiz;
        const float* pbhz = (const float*)&vbhz;
        const float* pbin = (const float*)&vbin;
        const float* pbhn = (const float*)&vbhn;

        size_t orow = ((size_t)(R0 + r) * TT + t) * HH + j0;
        float4 hprev = {0.f, 0.f, 0.f, 0.f};
        if (t > 0) hprev = *(const float4*)(out + orow - HH);
        const float* php = (const float*)&hprev;

        float4 hnew;
        float* phn = (float*)&hnew;
#pragma unroll
        for (int jj = 0; jj < 4; ++jj) {
            float rpre = p[jj * 4 + 0] + pbir[jj] + pbhr[jj];
            float zpre = p[jj * 4 + 1] + pbiz[jj] + pbhz[jj];
            float xn   = p[jj * 4 + 2] + pbin[jj];
            float hn   = p[jj * 4 + 3] + pbhn[jj];
            float rg = 1.f / (1.f + __expf(-rpre));
            float zg = 1.f / (1.f + __expf(-zpre));
            float ng = tanhf(xn + rg * hn);
            phn[jj] = (1.f - zg) * ng + zg * php[jj];
        }
        *(float4*)(out + orow) = hnew;
    }
}

extern "C" void kernel_launch(void* const* d_in, const int* in_sizes, int n_in,
                              void* d_out, int out_size, void* d_ws, size_t ws_size,
                              hipStream_t stream) {
    (void)in_sizes; (void)n_in; (void)d_ws; (void)ws_size; (void)out_size;

    const float* x    = (const float*)d_in[0];
    const float* Wir  = (const float*)d_in[1];
    const float* bir  = (const float*)d_in[2];
    const float* Whr  = (const float*)d_in[3];
    const float* bhr  = (const float*)d_in[4];
    const float* Wiz  = (const float*)d_in[5];
    const float* biz  = (const float*)d_in[6];
    const float* Whz  = (const float*)d_in[7];
    const float* bhz  = (const float*)d_in[8];
    const float* Win  = (const float*)d_in[9];
    const float* bin_ = (const float*)d_in[10];
    const float* Whn  = (const float*)d_in[11];
    const float* bhn  = (const float*)d_in[12];
    float* out = (float*)d_out;

    for (int t = 0; t < TT; ++t) {
        gru_step<<<dim3(256), dim3(256), 0, stream>>>(
            x, Wir, Whr, Wiz, Whz, Win, Whn,
            bir, bhr, biz, bhz, bin_, bhn, out, t);
    }
}